// Round 1
// 426.420 us; speedup vs baseline: 1.0178x; 1.0178x over previous
//
#include <hip/hip_runtime.h>

// B=4, Cin=Cout=64, H=W=128, K=9, PAD=1. NCHW fp32.
//
// Workspace layout (floats):
//   wt1  @ 0       (36864)  main weights layer1, [c][og][k][oi] (og=o/8, oi=o%8)
//   wt2  @ 36864   (36864)
//   wo1  @ 73728   (10368)  offset-conv weights layer1, [c][t][j] (j=0..17)
//   wo2  @ 84096   (10368)
//   bn1  @ 94464   (128)    scale[64], shift[64]
//   bn2  @ 94592   (128)
//   offb @ 94720   (1179648)  4*18*16384
//   hbuf @ 1274368 (4194304)  4*64*16384

// ---------------- prep: weight relayouts + BN constants ---------------------
__global__ __launch_bounds__(256) void prep_kernel(
    const float* __restrict__ w1, const float* __restrict__ w2,
    const float* __restrict__ woff1, const float* __restrict__ woff2,
    const float* __restrict__ g1, const float* __restrict__ be1,
    const float* __restrict__ m1, const float* __restrict__ v1,
    const float* __restrict__ g2, const float* __restrict__ be2,
    const float* __restrict__ m2, const float* __restrict__ v2,
    float* __restrict__ ws) {
  float* wt1 = ws;
  float* wt2 = ws + 36864;
  float* wo1 = ws + 73728;
  float* wo2 = ws + 84096;
  float* bn1 = ws + 94464;
  float* bn2 = ws + 94592;
  int idx = blockIdx.x * 256 + threadIdx.x;
  if (idx < 73728) {
    int t = (idx < 36864) ? idx : idx - 36864;
    const float* w = (idx < 36864) ? w1 : w2;
    float* wt = (idx < 36864) ? wt1 : wt2;
    int oi = t & 7;
    int rest = t >> 3;             // (c*8+og)*9 + k
    int k = rest % 9;
    int cog = rest / 9;
    int og = cog & 7, c = cog >> 3;
    int o = og * 8 + oi;
    wt[t] = w[(o * 64 + c) * 9 + k];
  } else if (idx < 94464) {
    int u = idx - 73728;
    int t2 = (u < 10368) ? u : u - 10368;
    const float* w = (u < 10368) ? woff1 : woff2;
    float* wo = (u < 10368) ? wo1 : wo2;
    int j = t2 % 18;
    int v = t2 / 18;               // c*9 + t
    int tt = v % 9;
    int c = v / 9;
    wo[t2] = w[(j * 64 + c) * 9 + tt];
  } else if (idx < 94528) {
    int o = idx - 94464;
    float s = g1[o] * rsqrtf(v1[o] + 1e-5f);
    bn1[o] = s;
    bn1[64 + o] = be1[o] - m1[o] * s;
  } else if (idx < 94592) {
    int o = idx - 94528;
    float s = g2[o] * rsqrtf(v2[o] + 1e-5f);
    bn2[o] = s;
    bn2[64 + o] = be2[o] - m2[o] * s;
  }
}

// ---------------- offset conv: 3x3, 64 -> 18 ch, zero pad -------------------
// Block = 512 threads: 64 px (one row segment) x 8 o-groups (2-3 o each).
// 8 waves/block, 4 blocks/CU -> 32 waves/CU (full occupancy).
// c-outer loop: 3-row halo of plane c staged in LDS (double-buffered).
__global__ __launch_bounds__(512, 8) void conv_off_kernel(
    const float* __restrict__ xin, const float* __restrict__ wofft,
    const float* __restrict__ boff, float* __restrict__ off) {
  __shared__ float halo[2][198];   // 3 rows x 66
  int tid = threadIdx.x;
  int pxl = tid & 63;
  int og = tid >> 6;
  int ogu = __builtin_amdgcn_readfirstlane(og);   // wave-uniform -> s_loads
  int p0 = blockIdx.x * 64;
  int b = p0 >> 14, hw0 = p0 & 16383;
  int h = hw0 >> 7, w0 = hw0 & 127;

  bool sv = tid < 198;
  int r = tid / 66, cc = tid - r * 66;
  int yy = h + r - 1, xx = w0 + cc - 1;
  bool inb = sv && (yy >= 0) && (yy < 128) && (xx >= 0) && (xx < 128);
  int ofs = (yy << 7) + xx;
  const float* xb0 = xin + ((size_t)(b * 64) << 14);

  float stg = inb ? xb0[ofs] : 0.f;

  // j-channel assignment: og 0,1 -> 3 outputs; og 2..7 -> 2 outputs.
  int jbase = (ogu < 2) ? ogu * 3 : 6 + (ogu - 2) * 2;
  int nj = (ogu < 2) ? 3 : 2;
  int jc2 = jbase + 2;
  if (jc2 > 17) jc2 = 17;          // clamp (result unused when nj==2)

  float acc[3] = {0.f, 0.f, 0.f};

#pragma unroll 1
  for (int c = 0; c < 64; ++c) {
    if (sv) halo[c & 1][tid] = stg;
    if (c < 63) stg = inb ? xb0[((size_t)(c + 1) << 14) + ofs] : 0.f;
    __syncthreads();
    const float* wc = wofft + c * 162;
#pragma unroll
    for (int t = 0; t < 9; ++t) {
      float v = halo[c & 1][(t / 3) * 66 + pxl + (t % 3)];
      acc[0] = fmaf(v, wc[t * 18 + jbase], acc[0]);
      acc[1] = fmaf(v, wc[t * 18 + jbase + 1], acc[1]);
      acc[2] = fmaf(v, wc[t * 18 + jc2], acc[2]);
    }
  }
#pragma unroll
  for (int i = 0; i < 3; ++i) {
    if (i < nj) {
      int j = jbase + i;
      off[((size_t)(b * 18 + j) << 14) + hw0 + pxl] = acc[i] + boff[j];
    }
  }
}

// ---------------- fused deformable sample + einsum + BN + ReLU --------------
// Block = 512 threads: 64 px x 8 o-groups (8 o each). 8 waves/block,
// 4 blocks/CU -> 32 waves/CU. c-outer loop; per c the block's 576 (px,k)
// samples are computed cooperatively into LDS (dbuf, 1 barrier/c),
// then each thread FMAs 9k x 8o with scalar weights.
__global__ __launch_bounds__(512, 8) void dcn_main_kernel(
    const float* __restrict__ xin, const float* __restrict__ off,
    const float* __restrict__ wt, const float* __restrict__ bn,
    float* __restrict__ out) {
  __shared__ float sbuf[2][576];
  int tid = threadIdx.x;
  int pxl = tid & 63;
  int og = tid >> 6;
  int ogu = __builtin_amdgcn_readfirstlane(og);
  int p0 = blockIdx.x * 64;
  int b = p0 >> 14, hw0 = p0 & 16383;
  int h = hw0 >> 7, w0 = hw0 & 127;
  const float* xb = xin + ((size_t)b << 20);

  // --- per-thread sampling params for up to 2 samples (s = tid + 512*j) ---
  float pw[2][4];
  int pi[2][4];
  bool act[2];
#pragma unroll
  for (int j = 0; j < 2; ++j) {
    bool a = (j == 0) || (tid < 64);
    act[j] = a;
    int s = tid + 512 * j;
    int k = s >> 6;
    if (k > 8) k = 8;
    int pxs = s & 63;
    int hw = hw0 + pxs;
    float dy = a ? off[((size_t)(b * 18 + 2 * k) << 14) + hw] : 0.f;
    float dx = a ? off[((size_t)(b * 18 + 2 * k + 1) << 14) + hw] : 0.f;
    float py = (float)(h + k / 3 - 1) + dy;
    float pxf = (float)(w0 + pxs + k % 3 - 1) + dx;
    float y0f = floorf(py), x0f = floorf(pxf);
    float wy1 = py - y0f, wx1 = pxf - x0f;
    float wy0 = 1.f - wy1, wx0 = 1.f - wx1;
    int y0 = (int)y0f, x0 = (int)x0f;
    int y1 = y0 + 1, x1 = x0 + 1;
    bool vy0 = (y0 >= 0) && (y0 <= 127);
    bool vy1 = (y1 >= 0) && (y1 <= 127);
    bool vx0 = (x0 >= 0) && (x0 <= 127);
    bool vx1 = (x1 >= 0) && (x1 <= 127);
    pw[j][0] = (vy0 && vx0) ? wy0 * wx0 : 0.f;
    pw[j][1] = (vy0 && vx1) ? wy0 * wx1 : 0.f;
    pw[j][2] = (vy1 && vx0) ? wy1 * wx0 : 0.f;
    pw[j][3] = (vy1 && vx1) ? wy1 * wx1 : 0.f;
    int y0c = min(max(y0, 0), 127), y1c = min(max(y1, 0), 127);
    int x0c = min(max(x0, 0), 127), x1c = min(max(x1, 0), 127);
    pi[j][0] = (y0c << 7) + x0c;
    pi[j][1] = (y0c << 7) + x1c;
    pi[j][2] = (y1c << 7) + x0c;
    pi[j][3] = (y1c << 7) + x1c;
  }

  // prologue: taps for c=0
  float tp[2][4];
#pragma unroll
  for (int j = 0; j < 2; ++j)
#pragma unroll
    for (int q = 0; q < 4; ++q) tp[j][q] = act[j] ? xb[pi[j][q]] : 0.f;

  float acc[8];
#pragma unroll
  for (int oi = 0; oi < 8; ++oi) acc[oi] = 0.f;

#pragma unroll 1
  for (int c = 0; c < 64; ++c) {
    // blend + stash to LDS
#pragma unroll
    for (int j = 0; j < 2; ++j) {
      if (act[j]) {
        float sval = fmaf(pw[j][0], tp[j][0],
                     fmaf(pw[j][1], tp[j][1],
                     fmaf(pw[j][2], tp[j][2], pw[j][3] * tp[j][3])));
        sbuf[c & 1][tid + 512 * j] = sval;
      }
    }
    // prefetch taps for c+1 (lands under this c's einsum)
    if (c < 63) {
      const float* xn = xb + ((size_t)(c + 1) << 14);
#pragma unroll
      for (int j = 0; j < 2; ++j)
#pragma unroll
        for (int q = 0; q < 4; ++q)
          if (act[j]) tp[j][q] = xn[pi[j][q]];
    }
    __syncthreads();
    const float* wc = wt + (c * 8 + ogu) * 72;   // [c][og][k][8], scalar
#pragma unroll
    for (int k = 0; k < 9; ++k) {
      float sval = sbuf[c & 1][k * 64 + pxl];
#pragma unroll
      for (int oi = 0; oi < 8; ++oi)
        acc[oi] = fmaf(sval, wc[k * 8 + oi], acc[oi]);
    }
  }

#pragma unroll
  for (int oi = 0; oi < 8; ++oi) {
    int o = ogu * 8 + oi;
    float rres = fmaf(acc[oi], bn[o], bn[64 + o]);
    out[((size_t)(b * 64 + o) << 14) + hw0 + pxl] = fmaxf(rres, 0.f);
  }
}

extern "C" void kernel_launch(void* const* d_in, const int* in_sizes, int n_in,
                              void* d_out, int out_size, void* d_ws, size_t ws_size,
                              hipStream_t stream) {
  const float* x      = (const float*)d_in[0];
  const float* w_off1 = (const float*)d_in[1];
  const float* b_off1 = (const float*)d_in[2];
  const float* w1     = (const float*)d_in[3];
  const float* g1     = (const float*)d_in[4];
  const float* be1    = (const float*)d_in[5];
  const float* m1     = (const float*)d_in[6];
  const float* v1     = (const float*)d_in[7];
  const float* w_off2 = (const float*)d_in[8];
  const float* b_off2 = (const float*)d_in[9];
  const float* w2     = (const float*)d_in[10];
  const float* g2     = (const float*)d_in[11];
  const float* be2    = (const float*)d_in[12];
  const float* m2     = (const float*)d_in[13];
  const float* v2     = (const float*)d_in[14];
  float* out = (float*)d_out;

  float* ws   = (float*)d_ws;
  float* wt1  = ws;
  float* wt2  = ws + 36864;
  float* wo1  = ws + 73728;
  float* wo2  = ws + 84096;
  float* bn1  = ws + 94464;
  float* bn2  = ws + 94592;
  float* offb = ws + 94720;
  float* hbuf = ws + 1274368;

  prep_kernel<<<370, 256, 0, stream>>>(w1, w2, w_off1, w_off2,
                                       g1, be1, m1, v1, g2, be2, m2, v2, ws);

  conv_off_kernel<<<1024, 512, 0, stream>>>(x, wo1, b_off1, offb);
  dcn_main_kernel<<<1024, 512, 0, stream>>>(x, offb, wt1, bn1, hbuf);

  conv_off_kernel<<<1024, 512, 0, stream>>>(hbuf, wo2, b_off2, offb);
  dcn_main_kernel<<<1024, 512, 0, stream>>>(hbuf, offb, wt2, bn2, out);
}

// Round 2
// 378.473 us; speedup vs baseline: 1.1468x; 1.1267x over previous
//
#include <hip/hip_runtime.h>

// B=4, Cin=Cout=64, H=W=128, K=9, PAD=1. NCHW fp32.
//
// Workspace layout (floats):
//   wt1  @ 0       (36864)  main weights layer1, [c][og][k][oi] (og=o/8, oi=o%8)
//   wt2  @ 36864   (36864)
//   wo1  @ 73728   (10368)  offset-conv weights layer1, [c][t][j] (j=0..17)
//   wo2  @ 84096   (10368)
//   bn1  @ 94464   (128)    scale[64], shift[64]
//   bn2  @ 94592   (128)
//   offb @ 94720   (1179648)  4*18*16384
//   hbuf @ 1274368 (4194304)  4*64*16384

// ---------------- prep: weight relayouts + BN constants ---------------------
__global__ __launch_bounds__(256) void prep_kernel(
    const float* __restrict__ w1, const float* __restrict__ w2,
    const float* __restrict__ woff1, const float* __restrict__ woff2,
    const float* __restrict__ g1, const float* __restrict__ be1,
    const float* __restrict__ m1, const float* __restrict__ v1,
    const float* __restrict__ g2, const float* __restrict__ be2,
    const float* __restrict__ m2, const float* __restrict__ v2,
    float* __restrict__ ws) {
  float* wt1 = ws;
  float* wt2 = ws + 36864;
  float* wo1 = ws + 73728;
  float* wo2 = ws + 84096;
  float* bn1 = ws + 94464;
  float* bn2 = ws + 94592;
  int idx = blockIdx.x * 256 + threadIdx.x;
  if (idx < 73728) {
    int t = (idx < 36864) ? idx : idx - 36864;
    const float* w = (idx < 36864) ? w1 : w2;
    float* wt = (idx < 36864) ? wt1 : wt2;
    int oi = t & 7;
    int rest = t >> 3;             // (c*8+og)*9 + k
    int k = rest % 9;
    int cog = rest / 9;
    int og = cog & 7, c = cog >> 3;
    int o = og * 8 + oi;
    wt[t] = w[(o * 64 + c) * 9 + k];
  } else if (idx < 94464) {
    int u = idx - 73728;
    int t2 = (u < 10368) ? u : u - 10368;
    const float* w = (u < 10368) ? woff1 : woff2;
    float* wo = (u < 10368) ? wo1 : wo2;
    int j = t2 % 18;
    int v = t2 / 18;               // c*9 + t
    int tt = v % 9;
    int c = v / 9;
    wo[t2] = w[(j * 64 + c) * 9 + tt];
  } else if (idx < 94528) {
    int o = idx - 94464;
    float s = g1[o] * rsqrtf(v1[o] + 1e-5f);
    bn1[o] = s;
    bn1[64 + o] = be1[o] - m1[o] * s;
  } else if (idx < 94592) {
    int o = idx - 94528;
    float s = g2[o] * rsqrtf(v2[o] + 1e-5f);
    bn2[o] = s;
    bn2[64 + o] = be2[o] - m2[o] * s;
  }
}

// ---------------- offset conv: 3x3, 64 -> 18 ch, zero pad -------------------
// Block = 512 threads: 64 px x 8 o-groups (2-3 o each). 8 waves/block,
// 4 blocks/CU -> 32 waves/CU. Two channels staged per barrier (32 barriers),
// double-buffered; prefetch distance = one 2-plane compute phase.
__global__ __launch_bounds__(512, 8) void conv_off_kernel(
    const float* __restrict__ xin, const float* __restrict__ wofft,
    const float* __restrict__ boff, float* __restrict__ off) {
  __shared__ float halo[2][396];   // [buf][plane*198 + pos], 2 planes/stage
  int tid = threadIdx.x;
  int pxl = tid & 63;
  int og = tid >> 6;
  int ogu = __builtin_amdgcn_readfirstlane(og);   // wave-uniform -> s_loads
  int p0 = blockIdx.x * 64;
  int b = p0 >> 14, hw0 = p0 & 16383;
  int h = hw0 >> 7, w0 = hw0 & 127;

  bool sv = tid < 396;
  int pl = (tid >= 198) ? 1 : 0;   // which of the 2 staged planes
  int pos = tid - pl * 198;
  int r = pos / 66, cc = pos - r * 66;
  int yy = h + r - 1, xx = w0 + cc - 1;
  bool inb = sv && (yy >= 0) && (yy < 128) && (xx >= 0) && (xx < 128);
  int ofs = ((pl << 14) + (yy << 7)) + xx;   // plane-relative (+pl plane)
  const float* xb0 = xin + ((size_t)(b * 64) << 14);

  float stg = inb ? xb0[ofs] : 0.f;

  // j-channel assignment: og 0,1 -> 3 outputs; og 2..7 -> 2 outputs.
  int jbase = (ogu < 2) ? ogu * 3 : 6 + (ogu - 2) * 2;
  int nj = (ogu < 2) ? 3 : 2;
  int jc2 = jbase + 2;
  if (jc2 > 17) jc2 = 17;          // clamp (result unused when nj==2)

  float acc[3] = {0.f, 0.f, 0.f};

#pragma unroll 1
  for (int c = 0; c < 64; c += 2) {
    if (sv) halo[(c >> 1) & 1][tid] = stg;
    if (c < 62) stg = inb ? xb0[((size_t)(c + 2) << 14) + ofs] : 0.f;
    __syncthreads();
    const float* hb = halo[(c >> 1) & 1];
#pragma unroll
    for (int p = 0; p < 2; ++p) {
      const float* wc = wofft + (c + p) * 162;
#pragma unroll
      for (int t = 0; t < 9; ++t) {
        float v = hb[p * 198 + (t / 3) * 66 + pxl + (t % 3)];
        acc[0] = fmaf(v, wc[t * 18 + jbase], acc[0]);
        acc[1] = fmaf(v, wc[t * 18 + jbase + 1], acc[1]);
        acc[2] = fmaf(v, wc[t * 18 + jc2], acc[2]);
      }
    }
  }
#pragma unroll
  for (int i = 0; i < 3; ++i) {
    if (i < nj) {
      int j = jbase + i;
      off[((size_t)(b * 18 + j) << 14) + hw0 + pxl] = acc[i] + boff[j];
    }
  }
}

// ---------------- fused deformable sample + einsum + BN + ReLU --------------
// Block = 512 threads: 64 px x 8 o-groups (8 o each). The gather path is the
// bottleneck (L1 line throughput): corners (y,x0)/(y,x0+1) are adjacent, so
// each row pair is ONE float2 gather + cndmask select -> 2 gathers/slot/c
// instead of 4. Extra 64 slots (k=8) spread over all 8 waves (1/8 lanes).
__global__ __launch_bounds__(512, 8) void dcn_main_kernel(
    const float* __restrict__ xin, const float* __restrict__ off,
    const float* __restrict__ wt, const float* __restrict__ bn,
    float* __restrict__ out) {
  __shared__ float sbuf[2][576];
  int tid = threadIdx.x;
  int pxl = tid & 63;
  int og = tid >> 6;
  int ogu = __builtin_amdgcn_readfirstlane(og);
  int p0 = blockIdx.x * 64;
  int b = p0 >> 14, hw0 = p0 & 16383;
  int h = hw0 >> 7, w0 = hw0 & 127;
  const float* xb = xin + ((size_t)b << 20);

  bool act1 = (tid & 7) == 0;      // slot1 handled by 1/8 of threads
  int s1 = 512 + (tid >> 3);       // slot id 512..575 (k=8)

  // --- per-slot sampling params: row-pair base addrs + weights + selects ---
  float pw0[4], pw1[4];
  int ra0, rb0, ra1, rb1;          // (row<<7)+xb for rows y0,y1 of each slot
  bool se0a, se1a, se0b, se1b;

#pragma unroll
  for (int j = 0; j < 2; ++j) {
    bool a = (j == 0) || act1;
    int s = (j == 0) ? tid : s1;
    int k = s >> 6;
    int pxs = s & 63;
    int hw = hw0 + pxs;
    float dy = a ? off[((size_t)(b * 18 + 2 * k) << 14) + hw] : 0.f;
    float dx = a ? off[((size_t)(b * 18 + 2 * k + 1) << 14) + hw] : 0.f;
    float py = (float)(h + k / 3 - 1) + dy;
    float pxf = (float)(w0 + pxs + k % 3 - 1) + dx;
    float y0f = floorf(py), x0f = floorf(pxf);
    float wy1 = py - y0f, wx1 = pxf - x0f;
    float wy0 = 1.f - wy1, wx0 = 1.f - wx1;
    int y0 = (int)y0f, x0 = (int)x0f;
    int y1 = y0 + 1, x1 = x0 + 1;
    bool vy0 = (y0 >= 0) && (y0 <= 127);
    bool vy1 = (y1 >= 0) && (y1 <= 127);
    bool vx0 = (x0 >= 0) && (x0 <= 127);
    bool vx1 = (x1 >= 0) && (x1 <= 127);
    float* pw = (j == 0) ? pw0 : pw1;
    pw[0] = (vy0 && vx0) ? wy0 * wx0 : 0.f;
    pw[1] = (vy0 && vx1) ? wy0 * wx1 : 0.f;
    pw[2] = (vy1 && vx0) ? wy1 * wx0 : 0.f;
    pw[3] = (vy1 && vx1) ? wy1 * wx1 : 0.f;
    int y0c = min(max(y0, 0), 127), y1c = min(max(y1, 0), 127);
    int xb2 = min(max(x0, 0), 126);
    // tap(x0) = (x0==xb2)? v.x : v.y ; tap(x0+1) = (x0+1==xb2)? v.x : v.y
    // (whenever the select picks the "wrong" element, that corner weight is 0)
    if (j == 0) {
      ra0 = (y0c << 7) + xb2; rb0 = (y1c << 7) + xb2;
      se0a = (x0 == xb2); se1a = (x0 + 1 == xb2);
    } else {
      ra1 = (y0c << 7) + xb2; rb1 = (y1c << 7) + xb2;
      se0b = (x0 == xb2); se1b = (x0 + 1 == xb2);
    }
  }

  // prologue: row-pair taps for c=0
  float2 t0a, t1a, t0b, t1b;
  t0a = *(const float2*)(xb + ra0);
  t1a = *(const float2*)(xb + rb0);
  t0b = act1 ? *(const float2*)(xb + ra1) : make_float2(0.f, 0.f);
  t1b = act1 ? *(const float2*)(xb + rb1) : make_float2(0.f, 0.f);

  float acc[8];
#pragma unroll
  for (int oi = 0; oi < 8; ++oi) acc[oi] = 0.f;

#pragma unroll 1
  for (int c = 0; c < 64; ++c) {
    // blend + stash to LDS
    {
      float v00 = se0a ? t0a.x : t0a.y;
      float v01 = se1a ? t0a.x : t0a.y;
      float v10 = se0a ? t1a.x : t1a.y;
      float v11 = se1a ? t1a.x : t1a.y;
      sbuf[c & 1][tid] = fmaf(pw0[0], v00,
                         fmaf(pw0[1], v01,
                         fmaf(pw0[2], v10, pw0[3] * v11)));
    }
    if (act1) {
      float v00 = se0b ? t0b.x : t0b.y;
      float v01 = se1b ? t0b.x : t0b.y;
      float v10 = se0b ? t1b.x : t1b.y;
      float v11 = se1b ? t1b.x : t1b.y;
      sbuf[c & 1][s1] = fmaf(pw1[0], v00,
                        fmaf(pw1[1], v01,
                        fmaf(pw1[2], v10, pw1[3] * v11)));
    }
    // prefetch row pairs for c+1 (lands under this c's einsum)
    if (c < 63) {
      const float* xn = xb + ((size_t)(c + 1) << 14);
      t0a = *(const float2*)(xn + ra0);
      t1a = *(const float2*)(xn + rb0);
      if (act1) {
        t0b = *(const float2*)(xn + ra1);
        t1b = *(const float2*)(xn + rb1);
      }
    }
    __syncthreads();
    const float* wc = wt + (c * 8 + ogu) * 72;   // [c][og][k][8], scalar
#pragma unroll
    for (int k = 0; k < 9; ++k) {
      float sval = sbuf[c & 1][k * 64 + pxl];
#pragma unroll
      for (int oi = 0; oi < 8; ++oi)
        acc[oi] = fmaf(sval, wc[k * 8 + oi], acc[oi]);
    }
  }

#pragma unroll
  for (int oi = 0; oi < 8; ++oi) {
    int o = ogu * 8 + oi;
    float rres = fmaf(acc[oi], bn[o], bn[64 + o]);
    out[((size_t)(b * 64 + o) << 14) + hw0 + pxl] = fmaxf(rres, 0.f);
  }
}

extern "C" void kernel_launch(void* const* d_in, const int* in_sizes, int n_in,
                              void* d_out, int out_size, void* d_ws, size_t ws_size,
                              hipStream_t stream) {
  const float* x      = (const float*)d_in[0];
  const float* w_off1 = (const float*)d_in[1];
  const float* b_off1 = (const float*)d_in[2];
  const float* w1     = (const float*)d_in[3];
  const float* g1     = (const float*)d_in[4];
  const float* be1    = (const float*)d_in[5];
  const float* m1     = (const float*)d_in[6];
  const float* v1     = (const float*)d_in[7];
  const float* w_off2 = (const float*)d_in[8];
  const float* b_off2 = (const float*)d_in[9];
  const float* w2     = (const float*)d_in[10];
  const float* g2     = (const float*)d_in[11];
  const float* be2    = (const float*)d_in[12];
  const float* m2     = (const float*)d_in[13];
  const float* v2     = (const float*)d_in[14];
  float* out = (float*)d_out;

  float* ws   = (float*)d_ws;
  float* wt1  = ws;
  float* wt2  = ws + 36864;
  float* wo1  = ws + 73728;
  float* wo2  = ws + 84096;
  float* bn1  = ws + 94464;
  float* bn2  = ws + 94592;
  float* offb = ws + 94720;
  float* hbuf = ws + 1274368;

  prep_kernel<<<370, 256, 0, stream>>>(w1, w2, w_off1, w_off2,
                                       g1, be1, m1, v1, g2, be2, m2, v2, ws);

  conv_off_kernel<<<1024, 512, 0, stream>>>(x, wo1, b_off1, offb);
  dcn_main_kernel<<<1024, 512, 0, stream>>>(x, offb, wt1, bn1, hbuf);

  conv_off_kernel<<<1024, 512, 0, stream>>>(hbuf, wo2, b_off2, offb);
  dcn_main_kernel<<<1024, 512, 0, stream>>>(hbuf, offb, wt2, bn2, out);
}

// Round 3
// 376.116 us; speedup vs baseline: 1.1540x; 1.0063x over previous
//
#include <hip/hip_runtime.h>

// B=4, Cin=Cout=64, H=W=128, K=9, PAD=1. NCHW fp32.
//
// Barrier note: __syncthreads() emits s_waitcnt vmcnt(0) lgkmcnt(0) before
// s_barrier, which drains the cross-iteration global prefetch every c-iter.
// LDS producer->consumer only needs lgkmcnt(0); BAR_LGKM keeps the gather
// loads in flight across the barrier (their vmcnt wait lands at the use).
#define BAR_LGKM()                                         \
  do {                                                     \
    asm volatile("s_waitcnt lgkmcnt(0)" ::: "memory");     \
    __builtin_amdgcn_s_barrier();                          \
  } while (0)

// Workspace layout (floats):
//   wt1  @ 0       (36864)  main weights layer1, [c][og][k][oi] (og=o/8, oi=o%8)
//   wt2  @ 36864   (36864)
//   wo1  @ 73728   (10368)  offset-conv weights layer1, [c][t][j] (j=0..17)
//   wo2  @ 84096   (10368)
//   bn1  @ 94464   (128)    scale[64], shift[64]
//   bn2  @ 94592   (128)
//   offb @ 94720   (1179648)  4*18*16384
//   hbuf @ 1274368 (4194304)  4*64*16384

// ---------------- prep: weight relayouts + BN constants ---------------------
__global__ __launch_bounds__(256) void prep_kernel(
    const float* __restrict__ w1, const float* __restrict__ w2,
    const float* __restrict__ woff1, const float* __restrict__ woff2,
    const float* __restrict__ g1, const float* __restrict__ be1,
    const float* __restrict__ m1, const float* __restrict__ v1,
    const float* __restrict__ g2, const float* __restrict__ be2,
    const float* __restrict__ m2, const float* __restrict__ v2,
    float* __restrict__ ws) {
  float* wt1 = ws;
  float* wt2 = ws + 36864;
  float* wo1 = ws + 73728;
  float* wo2 = ws + 84096;
  float* bn1 = ws + 94464;
  float* bn2 = ws + 94592;
  int idx = blockIdx.x * 256 + threadIdx.x;
  if (idx < 73728) {
    int t = (idx < 36864) ? idx : idx - 36864;
    const float* w = (idx < 36864) ? w1 : w2;
    float* wt = (idx < 36864) ? wt1 : wt2;
    int oi = t & 7;
    int rest = t >> 3;             // (c*8+og)*9 + k
    int k = rest % 9;
    int cog = rest / 9;
    int og = cog & 7, c = cog >> 3;
    int o = og * 8 + oi;
    wt[t] = w[(o * 64 + c) * 9 + k];
  } else if (idx < 94464) {
    int u = idx - 73728;
    int t2 = (u < 10368) ? u : u - 10368;
    const float* w = (u < 10368) ? woff1 : woff2;
    float* wo = (u < 10368) ? wo1 : wo2;
    int j = t2 % 18;
    int v = t2 / 18;               // c*9 + t
    int tt = v % 9;
    int c = v / 9;
    wo[t2] = w[(j * 64 + c) * 9 + tt];
  } else if (idx < 94528) {
    int o = idx - 94464;
    float s = g1[o] * rsqrtf(v1[o] + 1e-5f);
    bn1[o] = s;
    bn1[64 + o] = be1[o] - m1[o] * s;
  } else if (idx < 94592) {
    int o = idx - 94528;
    float s = g2[o] * rsqrtf(v2[o] + 1e-5f);
    bn2[o] = s;
    bn2[64 + o] = be2[o] - m2[o] * s;
  }
}

// ---------------- offset conv: 3x3, 64 -> 18 ch, zero pad -------------------
// Block = 512 threads: 64 px x 8 o-groups (2-3 o each). Two channels staged
// per barrier (32 barriers), double-buffered, lgkm-only barrier.
__global__ __launch_bounds__(512, 8) void conv_off_kernel(
    const float* __restrict__ xin, const float* __restrict__ wofft,
    const float* __restrict__ boff, float* __restrict__ off) {
  __shared__ float halo[2][396];   // [buf][plane*198 + pos], 2 planes/stage
  int tid = threadIdx.x;
  int pxl = tid & 63;
  int og = tid >> 6;
  int ogu = __builtin_amdgcn_readfirstlane(og);   // wave-uniform -> s_loads
  int p0 = blockIdx.x * 64;
  int b = p0 >> 14, hw0 = p0 & 16383;
  int h = hw0 >> 7, w0 = hw0 & 127;

  bool sv = tid < 396;
  int pl = (tid >= 198) ? 1 : 0;   // which of the 2 staged planes
  int pos = tid - pl * 198;
  int r = pos / 66, cc = pos - r * 66;
  int yy = h + r - 1, xx = w0 + cc - 1;
  bool inb = sv && (yy >= 0) && (yy < 128) && (xx >= 0) && (xx < 128);
  int ofs = ((pl << 14) + (yy << 7)) + xx;   // plane-relative (+pl plane)
  const float* xb0 = xin + ((size_t)(b * 64) << 14);

  float stg = inb ? xb0[ofs] : 0.f;

  // j-channel assignment: og 0,1 -> 3 outputs; og 2..7 -> 2 outputs.
  int jbase = (ogu < 2) ? ogu * 3 : 6 + (ogu - 2) * 2;
  int nj = (ogu < 2) ? 3 : 2;
  int jc2 = jbase + 2;
  if (jc2 > 17) jc2 = 17;          // clamp (result unused when nj==2)

  float acc[3] = {0.f, 0.f, 0.f};

#pragma unroll 1
  for (int c = 0; c < 64; c += 2) {
    if (sv) halo[(c >> 1) & 1][tid] = stg;
    if (c < 62) stg = inb ? xb0[((size_t)(c + 2) << 14) + ofs] : 0.f;
    BAR_LGKM();
    const float* hb = halo[(c >> 1) & 1];
#pragma unroll
    for (int p = 0; p < 2; ++p) {
      const float* wc = wofft + (c + p) * 162;
#pragma unroll
      for (int t = 0; t < 9; ++t) {
        float v = hb[p * 198 + (t / 3) * 66 + pxl + (t % 3)];
        acc[0] = fmaf(v, wc[t * 18 + jbase], acc[0]);
        acc[1] = fmaf(v, wc[t * 18 + jbase + 1], acc[1]);
        acc[2] = fmaf(v, wc[t * 18 + jc2], acc[2]);
      }
    }
    // readers of halo[cur] are done only after next iteration's barrier;
    // next write targets halo[cur^1], overwrite of halo[cur] is 2 iters
    // away with a barrier in between -> safe.
  }
#pragma unroll
  for (int i = 0; i < 3; ++i) {
    if (i < nj) {
      int j = jbase + i;
      off[((size_t)(b * 18 + j) << 14) + hw0 + pxl] = acc[i] + boff[j];
    }
  }
}

// ---------------- fused deformable sample + einsum + BN + ReLU --------------
// Block = 512 threads: 64 px x 8 o-groups (8 o each). Row-pair float2 gathers
// + cndmask select (2 gathers/slot/c). lgkm-only barrier lets the c+1 gather
// prefetch stay in flight across the barrier (covered by the einsum).
__global__ __launch_bounds__(512, 8) void dcn_main_kernel(
    const float* __restrict__ xin, const float* __restrict__ off,
    const float* __restrict__ wt, const float* __restrict__ bn,
    float* __restrict__ out) {
  __shared__ float sbuf[2][576];
  int tid = threadIdx.x;
  int pxl = tid & 63;
  int og = tid >> 6;
  int ogu = __builtin_amdgcn_readfirstlane(og);
  int p0 = blockIdx.x * 64;
  int b = p0 >> 14, hw0 = p0 & 16383;
  int h = hw0 >> 7, w0 = hw0 & 127;
  const float* xb = xin + ((size_t)b << 20);

  bool act1 = (tid & 7) == 0;      // slot1 handled by 1/8 of threads
  int s1 = 512 + (tid >> 3);       // slot id 512..575 (k=8)

  // --- per-slot sampling params: row-pair base addrs + weights + selects ---
  float pw0[4], pw1[4];
  int ra0, rb0, ra1, rb1;          // (row<<7)+xb for rows y0,y1 of each slot
  bool se0a, se1a, se0b, se1b;

#pragma unroll
  for (int j = 0; j < 2; ++j) {
    bool a = (j == 0) || act1;
    int s = (j == 0) ? tid : s1;
    int k = s >> 6;
    int pxs = s & 63;
    int hw = hw0 + pxs;
    float dy = a ? off[((size_t)(b * 18 + 2 * k) << 14) + hw] : 0.f;
    float dx = a ? off[((size_t)(b * 18 + 2 * k + 1) << 14) + hw] : 0.f;
    float py = (float)(h + k / 3 - 1) + dy;
    float pxf = (float)(w0 + pxs + k % 3 - 1) + dx;
    float y0f = floorf(py), x0f = floorf(pxf);
    float wy1 = py - y0f, wx1 = pxf - x0f;
    float wy0 = 1.f - wy1, wx0 = 1.f - wx1;
    int y0 = (int)y0f, x0 = (int)x0f;
    int y1 = y0 + 1, x1 = x0 + 1;
    bool vy0 = (y0 >= 0) && (y0 <= 127);
    bool vy1 = (y1 >= 0) && (y1 <= 127);
    bool vx0 = (x0 >= 0) && (x0 <= 127);
    bool vx1 = (x1 >= 0) && (x1 <= 127);
    float* pw = (j == 0) ? pw0 : pw1;
    pw[0] = (vy0 && vx0) ? wy0 * wx0 : 0.f;
    pw[1] = (vy0 && vx1) ? wy0 * wx1 : 0.f;
    pw[2] = (vy1 && vx0) ? wy1 * wx0 : 0.f;
    pw[3] = (vy1 && vx1) ? wy1 * wx1 : 0.f;
    int y0c = min(max(y0, 0), 127), y1c = min(max(y1, 0), 127);
    int xb2 = min(max(x0, 0), 126);
    // tap(x0) = (x0==xb2)? v.x : v.y ; tap(x0+1) = (x0+1==xb2)? v.x : v.y
    // (whenever the select picks the "wrong" element, that corner weight is 0)
    if (j == 0) {
      ra0 = (y0c << 7) + xb2; rb0 = (y1c << 7) + xb2;
      se0a = (x0 == xb2); se1a = (x0 + 1 == xb2);
    } else {
      ra1 = (y0c << 7) + xb2; rb1 = (y1c << 7) + xb2;
      se0b = (x0 == xb2); se1b = (x0 + 1 == xb2);
    }
  }

  // prologue: row-pair taps for c=0
  float2 t0a, t1a, t0b, t1b;
  t0a = *(const float2*)(xb + ra0);
  t1a = *(const float2*)(xb + rb0);
  t0b = act1 ? *(const float2*)(xb + ra1) : make_float2(0.f, 0.f);
  t1b = act1 ? *(const float2*)(xb + rb1) : make_float2(0.f, 0.f);

  float acc[8];
#pragma unroll
  for (int oi = 0; oi < 8; ++oi) acc[oi] = 0.f;

#pragma unroll 1
  for (int c = 0; c < 64; ++c) {
    // blend + stash to LDS
    {
      float v00 = se0a ? t0a.x : t0a.y;
      float v01 = se1a ? t0a.x : t0a.y;
      float v10 = se0a ? t1a.x : t1a.y;
      float v11 = se1a ? t1a.x : t1a.y;
      sbuf[c & 1][tid] = fmaf(pw0[0], v00,
                         fmaf(pw0[1], v01,
                         fmaf(pw0[2], v10, pw0[3] * v11)));
    }
    if (act1) {
      float v00 = se0b ? t0b.x : t0b.y;
      float v01 = se1b ? t0b.x : t0b.y;
      float v10 = se0b ? t1b.x : t1b.y;
      float v11 = se1b ? t1b.x : t1b.y;
      sbuf[c & 1][s1] = fmaf(pw1[0], v00,
                        fmaf(pw1[1], v01,
                        fmaf(pw1[2], v10, pw1[3] * v11)));
    }
    // prefetch row pairs for c+1 (stays in flight across the lgkm barrier;
    // vmcnt wait lands at next iteration's blend)
    if (c < 63) {
      const float* xn = xb + ((size_t)(c + 1) << 14);
      t0a = *(const float2*)(xn + ra0);
      t1a = *(const float2*)(xn + rb0);
      if (act1) {
        t0b = *(const float2*)(xn + ra1);
        t1b = *(const float2*)(xn + rb1);
      }
    }
    BAR_LGKM();
    const float* wc = wt + (c * 8 + ogu) * 72;   // [c][og][k][8], scalar
#pragma unroll
    for (int k = 0; k < 9; ++k) {
      float sval = sbuf[c & 1][k * 64 + pxl];
#pragma unroll
      for (int oi = 0; oi < 8; ++oi)
        acc[oi] = fmaf(sval, wc[k * 8 + oi], acc[oi]);
    }
  }

#pragma unroll
  for (int oi = 0; oi < 8; ++oi) {
    int o = ogu * 8 + oi;
    float rres = fmaf(acc[oi], bn[o], bn[64 + o]);
    out[((size_t)(b * 64 + o) << 14) + hw0 + pxl] = fmaxf(rres, 0.f);
  }
}

extern "C" void kernel_launch(void* const* d_in, const int* in_sizes, int n_in,
                              void* d_out, int out_size, void* d_ws, size_t ws_size,
                              hipStream_t stream) {
  const float* x      = (const float*)d_in[0];
  const float* w_off1 = (const float*)d_in[1];
  const float* b_off1 = (const float*)d_in[2];
  const float* w1     = (const float*)d_in[3];
  const float* g1     = (const float*)d_in[4];
  const float* be1    = (const float*)d_in[5];
  const float* m1     = (const float*)d_in[6];
  const float* v1     = (const float*)d_in[7];
  const float* w_off2 = (const float*)d_in[8];
  const float* b_off2 = (const float*)d_in[9];
  const float* w2     = (const float*)d_in[10];
  const float* g2     = (const float*)d_in[11];
  const float* be2    = (const float*)d_in[12];
  const float* m2     = (const float*)d_in[13];
  const float* v2     = (const float*)d_in[14];
  float* out = (float*)d_out;

  float* ws   = (float*)d_ws;
  float* wt1  = ws;
  float* wt2  = ws + 36864;
  float* wo1  = ws + 73728;
  float* wo2  = ws + 84096;
  float* bn1  = ws + 94464;
  float* bn2  = ws + 94592;
  float* offb = ws + 94720;
  float* hbuf = ws + 1274368;

  prep_kernel<<<370, 256, 0, stream>>>(w1, w2, w_off1, w_off2,
                                       g1, be1, m1, v1, g2, be2, m2, v2, ws);

  conv_off_kernel<<<1024, 512, 0, stream>>>(x, wo1, b_off1, offb);
  dcn_main_kernel<<<1024, 512, 0, stream>>>(x, offb, wt1, bn1, hbuf);

  conv_off_kernel<<<1024, 512, 0, stream>>>(hbuf, wo2, b_off2, offb);
  dcn_main_kernel<<<1024, 512, 0, stream>>>(hbuf, offb, wt2, bn2, out);
}